// Round 1
// baseline (2579.860 us; speedup 1.0000x reference)
//
#include <hip/hip_runtime.h>

#define NN 40000
#define NE 640000
#define DD 128
#define K3 384
#define BM 128
#define BK 32
#define LDA 33  // padded LDS row stride (breaks bank aliasing)

// ---------------- Stage A: m_node[dst] += relu(concat(x[dst],x[src],h) @ W1^T) ----
__global__ __launch_bounds__(256, 4)
void stageA(const float* __restrict__ x, const float* __restrict__ h,
            const float* __restrict__ W1, const int* __restrict__ src,
            const int* __restrict__ dst, float* __restrict__ m_node)
{
    __shared__ float As[BM * LDA];
    __shared__ float Ws[DD * LDA];
    __shared__ int dstS[BM], srcS[BM];

    const int t = threadIdx.x;
    const int e0 = blockIdx.x * BM;
    if (t < BM) { dstS[t] = dst[e0 + t]; srcS[t] = src[e0 + t]; }
    __syncthreads();

    const int tx = t & 15, ty = t >> 4;
    float acc[8][8];
    #pragma unroll
    for (int i = 0; i < 8; ++i)
        #pragma unroll
        for (int j = 0; j < 8; ++j) acc[i][j] = 0.f;

    for (int kt = 0; kt < 12; ++kt) {
        // A tile: rows gathered per concat segment, coalesced float4 within row
        #pragma unroll
        for (int i = 0; i < 4; ++i) {
            int idx = i * 256 + t;
            int m = idx >> 3, c4 = idx & 7;
            const float* rp;
            if (kt < 4)      rp = x + (size_t)dstS[m] * DD + kt * BK;
            else if (kt < 8) rp = x + (size_t)srcS[m] * DD + (kt - 4) * BK;
            else             rp = h + (size_t)(e0 + m) * DD + (kt - 8) * BK;
            float4 v = *(const float4*)(rp + c4 * 4);
            float* w = As + m * LDA + c4 * 4;
            w[0] = v.x; w[1] = v.y; w[2] = v.z; w[3] = v.w;
        }
        // W1 tile: Ws[d][c] = W1[d][kt*32+c]
        #pragma unroll
        for (int i = 0; i < 4; ++i) {
            int idx = i * 256 + t;
            int d = idx >> 3, c4 = idx & 7;
            float4 v = *(const float4*)(W1 + d * K3 + kt * BK + c4 * 4);
            float* w = Ws + d * LDA + c4 * 4;
            w[0] = v.x; w[1] = v.y; w[2] = v.z; w[3] = v.w;
        }
        __syncthreads();
        #pragma unroll 8
        for (int f = 0; f < BK; ++f) {
            float a[8], b[8];
            #pragma unroll
            for (int i = 0; i < 8; ++i) a[i] = As[(ty * 8 + i) * LDA + f];
            #pragma unroll
            for (int j = 0; j < 4; ++j) {
                b[j]     = Ws[(tx * 4 + j) * LDA + f];
                b[4 + j] = Ws[(64 + tx * 4 + j) * LDA + f];
            }
            #pragma unroll
            for (int i = 0; i < 8; ++i)
                #pragma unroll
                for (int j = 0; j < 8; ++j)
                    acc[i][j] = fmaf(a[i], b[j], acc[i][j]);
        }
        __syncthreads();
    }
    // relu + atomic scatter-add into m_node[dst]
    #pragma unroll
    for (int i = 0; i < 8; ++i) {
        int m = ty * 8 + i;
        float* mp = m_node + (size_t)dstS[m] * DD;
        #pragma unroll
        for (int j = 0; j < 4; ++j) {
            atomicAdd(mp + tx * 4 + j,      fmaxf(acc[i][j],     0.f));
            atomicAdd(mp + 64 + tx * 4 + j, fmaxf(acc[i][4 + j], 0.f));
        }
    }
}

// ---------------- Stage B: out = relu(LN(snorm * (m_node[src] @ W2^T))) ----------
__global__ __launch_bounds__(256, 4)
void stageB(const float* __restrict__ m_node, const float* __restrict__ W2,
            const float* __restrict__ snorm_n, const float* __restrict__ gamma,
            const float* __restrict__ beta, const int* __restrict__ src,
            float* __restrict__ out)
{
    __shared__ float As[BM * LDA];
    __shared__ float Ws[DD * LDA];
    __shared__ int srcS[BM];

    const int t = threadIdx.x;
    const int e0 = blockIdx.x * BM;
    if (t < BM) srcS[t] = src[e0 + t];
    __syncthreads();

    const int tx = t & 15, ty = t >> 4;
    float acc[8][8];
    #pragma unroll
    for (int i = 0; i < 8; ++i)
        #pragma unroll
        for (int j = 0; j < 8; ++j) acc[i][j] = 0.f;

    for (int kt = 0; kt < 4; ++kt) {
        #pragma unroll
        for (int i = 0; i < 4; ++i) {
            int idx = i * 256 + t;
            int m = idx >> 3, c4 = idx & 7;
            const float* rp = m_node + (size_t)srcS[m] * DD + kt * BK;
            float4 v = *(const float4*)(rp + c4 * 4);
            float* w = As + m * LDA + c4 * 4;
            w[0] = v.x; w[1] = v.y; w[2] = v.z; w[3] = v.w;
        }
        #pragma unroll
        for (int i = 0; i < 4; ++i) {
            int idx = i * 256 + t;
            int d = idx >> 3, c4 = idx & 7;
            float4 v = *(const float4*)(W2 + d * DD + kt * BK + c4 * 4);
            float* w = Ws + d * LDA + c4 * 4;
            w[0] = v.x; w[1] = v.y; w[2] = v.z; w[3] = v.w;
        }
        __syncthreads();
        #pragma unroll 8
        for (int f = 0; f < BK; ++f) {
            float a[8], b[8];
            #pragma unroll
            for (int i = 0; i < 8; ++i) a[i] = As[(ty * 8 + i) * LDA + f];
            #pragma unroll
            for (int j = 0; j < 4; ++j) {
                b[j]     = Ws[(tx * 4 + j) * LDA + f];
                b[4 + j] = Ws[(64 + tx * 4 + j) * LDA + f];
            }
            #pragma unroll
            for (int i = 0; i < 8; ++i)
                #pragma unroll
                for (int j = 0; j < 8; ++j)
                    acc[i][j] = fmaf(a[i], b[j], acc[i][j]);
        }
        __syncthreads();
    }

    // epilogue: graph-norm scale, LayerNorm over d (row spread across 16 tx lanes), relu
    float g1[4], g2[4], b1[4], b2[4];
    #pragma unroll
    for (int j = 0; j < 4; ++j) {
        g1[j] = gamma[tx * 4 + j];      b1[j] = beta[tx * 4 + j];
        g2[j] = gamma[64 + tx * 4 + j]; b2[j] = beta[64 + tx * 4 + j];
    }
    float sums[8], sqs[8];
    #pragma unroll
    for (int i = 0; i < 8; ++i) {
        float sc = snorm_n[e0 + ty * 8 + i];
        float ps = 0.f, pq = 0.f;
        #pragma unroll
        for (int j = 0; j < 8; ++j) {
            float v = acc[i][j] * sc;
            acc[i][j] = v;
            ps += v; pq += v * v;
        }
        sums[i] = ps; sqs[i] = pq;
    }
    #pragma unroll
    for (int off = 1; off < 16; off <<= 1) {
        #pragma unroll
        for (int i = 0; i < 8; ++i) {
            sums[i] += __shfl_xor(sums[i], off);
            sqs[i]  += __shfl_xor(sqs[i],  off);
        }
    }
    #pragma unroll
    for (int i = 0; i < 8; ++i) {
        float mu  = sums[i] * (1.f / 128.f);
        float var = sqs[i] * (1.f / 128.f) - mu * mu;
        float rs  = rsqrtf(var + 1e-5f);
        int e = e0 + ty * 8 + i;
        float4 o1, o2;
        o1.x = fmaxf((acc[i][0] - mu) * rs * g1[0] + b1[0], 0.f);
        o1.y = fmaxf((acc[i][1] - mu) * rs * g1[1] + b1[1], 0.f);
        o1.z = fmaxf((acc[i][2] - mu) * rs * g1[2] + b1[2], 0.f);
        o1.w = fmaxf((acc[i][3] - mu) * rs * g1[3] + b1[3], 0.f);
        o2.x = fmaxf((acc[i][4] - mu) * rs * g2[0] + b2[0], 0.f);
        o2.y = fmaxf((acc[i][5] - mu) * rs * g2[1] + b2[1], 0.f);
        o2.z = fmaxf((acc[i][6] - mu) * rs * g2[2] + b2[2], 0.f);
        o2.w = fmaxf((acc[i][7] - mu) * rs * g2[3] + b2[3], 0.f);
        *(float4*)(out + (size_t)e * DD + tx * 4)      = o1;
        *(float4*)(out + (size_t)e * DD + 64 + tx * 4) = o2;
    }
}

extern "C" void kernel_launch(void* const* d_in, const int* in_sizes, int n_in,
                              void* d_out, int out_size, void* d_ws, size_t ws_size,
                              hipStream_t stream) {
    const float* x       = (const float*)d_in[0];
    const float* h       = (const float*)d_in[1];
    const float* snorm_n = (const float*)d_in[2];
    // d_in[3] = snorm_e (unused by reference)
    const float* W1      = (const float*)d_in[4];
    const float* W2      = (const float*)d_in[5];
    const float* gamma   = (const float*)d_in[6];
    const float* beta    = (const float*)d_in[7];
    const int*   src     = (const int*)d_in[8];
    const int*   dst     = (const int*)d_in[9];
    float* out    = (float*)d_out;
    float* m_node = (float*)d_ws;  // 40000*128 fp32 = 20.48 MB accumulator

    hipMemsetAsync(m_node, 0, (size_t)NN * DD * sizeof(float), stream);
    stageA<<<NE / BM, 256, 0, stream>>>(x, h, W1, src, dst, m_node);
    stageB<<<NE / BM, 256, 0, stream>>>(m_node, W2, snorm_n, gamma, beta, src, out);
}

// Round 2
// 2487.460 us; speedup vs baseline: 1.0371x; 1.0371x over previous
//
#include <hip/hip_runtime.h>

#define NN 40000
#define NE 640000
#define DD 128
#define K3 384
#define BM 128
#define BK 32
#define LDA 33   // padded LDS row stride
#define NTILES 313  // ceil(40000/128)

// ---------- P,Q = x @ W1a^T , x @ W1b^T  (blockIdx.y selects column block of W1) ----
__global__ __launch_bounds__(256, 4)
void pq_kernel(const float* __restrict__ x, const float* __restrict__ W1,
               float* __restrict__ P, float* __restrict__ Q)
{
    __shared__ float As[BM * LDA];
    __shared__ float Ws[DD * LDA];
    const int t = threadIdx.x;
    const int n0 = blockIdx.x * BM;
    const int off = blockIdx.y * DD;          // 0 -> P (x[dst] slot), 128 -> Q (x[src] slot)
    float* __restrict__ OUT = blockIdx.y == 0 ? P : Q;
    const int tx = t & 15, ty = t >> 4;

    float acc[8][8];
    #pragma unroll
    for (int i = 0; i < 8; ++i)
        #pragma unroll
        for (int j = 0; j < 8; ++j) acc[i][j] = 0.f;

    for (int kt = 0; kt < 4; ++kt) {
        #pragma unroll
        for (int i = 0; i < 4; ++i) {
            int idx = i * 256 + t, m = idx >> 3, c4 = idx & 7;
            int n = n0 + m; if (n >= NN) n = NN - 1;
            float4 v = *(const float4*)(x + (size_t)n * DD + kt * BK + c4 * 4);
            float* w = As + m * LDA + c4 * 4;
            w[0] = v.x; w[1] = v.y; w[2] = v.z; w[3] = v.w;
        }
        #pragma unroll
        for (int i = 0; i < 4; ++i) {
            int idx = i * 256 + t, d = idx >> 3, c4 = idx & 7;
            float4 v = *(const float4*)(W1 + (size_t)d * K3 + off + kt * BK + c4 * 4);
            float* w = Ws + d * LDA + c4 * 4;
            w[0] = v.x; w[1] = v.y; w[2] = v.z; w[3] = v.w;
        }
        __syncthreads();
        #pragma unroll 8
        for (int f = 0; f < BK; ++f) {
            float a[8], b[8];
            #pragma unroll
            for (int i = 0; i < 8; ++i) a[i] = As[(ty * 8 + i) * LDA + f];
            #pragma unroll
            for (int j = 0; j < 4; ++j) {
                b[j]     = Ws[(tx * 4 + j) * LDA + f];
                b[4 + j] = Ws[(64 + tx * 4 + j) * LDA + f];
            }
            #pragma unroll
            for (int i = 0; i < 8; ++i)
                #pragma unroll
                for (int j = 0; j < 8; ++j)
                    acc[i][j] = fmaf(a[i], b[j], acc[i][j]);
        }
        __syncthreads();
    }
    #pragma unroll
    for (int i = 0; i < 8; ++i) {
        int n = n0 + ty * 8 + i;
        if (n < NN) {
            float4 o1 = { acc[i][0], acc[i][1], acc[i][2], acc[i][3] };
            float4 o2 = { acc[i][4], acc[i][5], acc[i][6], acc[i][7] };
            *(float4*)(OUT + (size_t)n * DD + tx * 4)      = o1;
            *(float4*)(OUT + (size_t)n * DD + 64 + tx * 4) = o2;
        }
    }
}

// ---------- R = h @ W1c^T; m_node[dst] += relu(R + P[dst] + Q[src]) ----------------
__global__ __launch_bounds__(256, 4)
void r_scatter(const float* __restrict__ h, const float* __restrict__ W1,
               const float* __restrict__ P, const float* __restrict__ Q,
               const int* __restrict__ src, const int* __restrict__ dst,
               float* __restrict__ m_node)
{
    __shared__ float As[BM * LDA];
    __shared__ float Ws[DD * LDA];
    __shared__ int dstS[BM], srcS[BM];

    const int t = threadIdx.x;
    const int e0 = blockIdx.x * BM;
    if (t < BM) { dstS[t] = dst[e0 + t]; srcS[t] = src[e0 + t]; }
    const int tx = t & 15, ty = t >> 4;

    float acc[8][8];
    #pragma unroll
    for (int i = 0; i < 8; ++i)
        #pragma unroll
        for (int j = 0; j < 8; ++j) acc[i][j] = 0.f;

    for (int kt = 0; kt < 4; ++kt) {
        #pragma unroll
        for (int i = 0; i < 4; ++i) {
            int idx = i * 256 + t, m = idx >> 3, c4 = idx & 7;
            float4 v = *(const float4*)(h + (size_t)(e0 + m) * DD + kt * BK + c4 * 4);
            float* w = As + m * LDA + c4 * 4;
            w[0] = v.x; w[1] = v.y; w[2] = v.z; w[3] = v.w;
        }
        #pragma unroll
        for (int i = 0; i < 4; ++i) {
            int idx = i * 256 + t, d = idx >> 3, c4 = idx & 7;
            float4 v = *(const float4*)(W1 + (size_t)d * K3 + 256 + kt * BK + c4 * 4);
            float* w = Ws + d * LDA + c4 * 4;
            w[0] = v.x; w[1] = v.y; w[2] = v.z; w[3] = v.w;
        }
        __syncthreads();
        #pragma unroll 8
        for (int f = 0; f < BK; ++f) {
            float a[8], b[8];
            #pragma unroll
            for (int i = 0; i < 8; ++i) a[i] = As[(ty * 8 + i) * LDA + f];
            #pragma unroll
            for (int j = 0; j < 4; ++j) {
                b[j]     = Ws[(tx * 4 + j) * LDA + f];
                b[4 + j] = Ws[(64 + tx * 4 + j) * LDA + f];
            }
            #pragma unroll
            for (int i = 0; i < 8; ++i)
                #pragma unroll
                for (int j = 0; j < 8; ++j)
                    acc[i][j] = fmaf(a[i], b[j], acc[i][j]);
        }
        __syncthreads();
    }

    #pragma unroll
    for (int i = 0; i < 8; ++i) {
        int m = ty * 8 + i;
        int dn = dstS[m], sn = srcS[m];
        const float* Pp = P + (size_t)dn * DD;
        const float* Qp = Q + (size_t)sn * DD;
        float* mp = m_node + (size_t)dn * DD;
        float4 p1 = *(const float4*)(Pp + tx * 4);
        float4 q1 = *(const float4*)(Qp + tx * 4);
        float4 p2 = *(const float4*)(Pp + 64 + tx * 4);
        float4 q2 = *(const float4*)(Qp + 64 + tx * 4);
        atomicAdd(mp + tx * 4 + 0,      fmaxf(acc[i][0] + p1.x + q1.x, 0.f));
        atomicAdd(mp + tx * 4 + 1,      fmaxf(acc[i][1] + p1.y + q1.y, 0.f));
        atomicAdd(mp + tx * 4 + 2,      fmaxf(acc[i][2] + p1.z + q1.z, 0.f));
        atomicAdd(mp + tx * 4 + 3,      fmaxf(acc[i][3] + p1.w + q1.w, 0.f));
        atomicAdd(mp + 64 + tx * 4 + 0, fmaxf(acc[i][4] + p2.x + q2.x, 0.f));
        atomicAdd(mp + 64 + tx * 4 + 1, fmaxf(acc[i][5] + p2.y + q2.y, 0.f));
        atomicAdd(mp + 64 + tx * 4 + 2, fmaxf(acc[i][6] + p2.z + q2.z, 0.f));
        atomicAdd(mp + 64 + tx * 4 + 3, fmaxf(acc[i][7] + p2.w + q2.w, 0.f));
    }
}

// ---------- T = m_node @ W2^T ------------------------------------------------------
__global__ __launch_bounds__(256, 4)
void t_kernel(const float* __restrict__ m_node, const float* __restrict__ W2,
              float* __restrict__ T)
{
    __shared__ float As[BM * LDA];
    __shared__ float Ws[DD * LDA];
    const int t = threadIdx.x;
    const int n0 = blockIdx.x * BM;
    const int tx = t & 15, ty = t >> 4;

    float acc[8][8];
    #pragma unroll
    for (int i = 0; i < 8; ++i)
        #pragma unroll
        for (int j = 0; j < 8; ++j) acc[i][j] = 0.f;

    for (int kt = 0; kt < 4; ++kt) {
        #pragma unroll
        for (int i = 0; i < 4; ++i) {
            int idx = i * 256 + t, m = idx >> 3, c4 = idx & 7;
            int n = n0 + m; if (n >= NN) n = NN - 1;
            float4 v = *(const float4*)(m_node + (size_t)n * DD + kt * BK + c4 * 4);
            float* w = As + m * LDA + c4 * 4;
            w[0] = v.x; w[1] = v.y; w[2] = v.z; w[3] = v.w;
        }
        #pragma unroll
        for (int i = 0; i < 4; ++i) {
            int idx = i * 256 + t, d = idx >> 3, c4 = idx & 7;
            float4 v = *(const float4*)(W2 + (size_t)d * DD + kt * BK + c4 * 4);
            float* w = Ws + d * LDA + c4 * 4;
            w[0] = v.x; w[1] = v.y; w[2] = v.z; w[3] = v.w;
        }
        __syncthreads();
        #pragma unroll 8
        for (int f = 0; f < BK; ++f) {
            float a[8], b[8];
            #pragma unroll
            for (int i = 0; i < 8; ++i) a[i] = As[(ty * 8 + i) * LDA + f];
            #pragma unroll
            for (int j = 0; j < 4; ++j) {
                b[j]     = Ws[(tx * 4 + j) * LDA + f];
                b[4 + j] = Ws[(64 + tx * 4 + j) * LDA + f];
            }
            #pragma unroll
            for (int i = 0; i < 8; ++i)
                #pragma unroll
                for (int j = 0; j < 8; ++j)
                    acc[i][j] = fmaf(a[i], b[j], acc[i][j]);
        }
        __syncthreads();
    }
    #pragma unroll
    for (int i = 0; i < 8; ++i) {
        int n = n0 + ty * 8 + i;
        if (n < NN) {
            float4 o1 = { acc[i][0], acc[i][1], acc[i][2], acc[i][3] };
            float4 o2 = { acc[i][4], acc[i][5], acc[i][6], acc[i][7] };
            *(float4*)(T + (size_t)n * DD + tx * 4)      = o1;
            *(float4*)(T + (size_t)n * DD + 64 + tx * 4) = o2;
        }
    }
}

// ---------- out = relu(LN(T[src] * snorm_n)) — 32 lanes per edge row ---------------
__global__ __launch_bounds__(256, 8)
void final_kernel(const float* __restrict__ T, const float* __restrict__ snorm_n,
                  const float* __restrict__ gamma, const float* __restrict__ beta,
                  const int* __restrict__ src, float* __restrict__ out)
{
    const int t = threadIdx.x;
    const int l = t & 31;
    const int e = blockIdx.x * 8 + (t >> 5);
    const int s = src[e];
    const float sc = snorm_n[e];
    float4 v = *(const float4*)(T + (size_t)s * DD + l * 4);
    v.x *= sc; v.y *= sc; v.z *= sc; v.w *= sc;
    float sum = v.x + v.y + v.z + v.w;
    float sq  = v.x * v.x + v.y * v.y + v.z * v.z + v.w * v.w;
    #pragma unroll
    for (int off = 1; off < 32; off <<= 1) {
        sum += __shfl_xor(sum, off);
        sq  += __shfl_xor(sq,  off);
    }
    float mu  = sum * (1.f / 128.f);
    float var = sq * (1.f / 128.f) - mu * mu;
    float rs  = rsqrtf(var + 1e-5f);
    float4 g = *(const float4*)(gamma + l * 4);
    float4 b = *(const float4*)(beta  + l * 4);
    float4 o;
    o.x = fmaxf((v.x - mu) * rs * g.x + b.x, 0.f);
    o.y = fmaxf((v.y - mu) * rs * g.y + b.y, 0.f);
    o.z = fmaxf((v.z - mu) * rs * g.z + b.z, 0.f);
    o.w = fmaxf((v.w - mu) * rs * g.w + b.w, 0.f);
    *(float4*)(out + (size_t)e * DD + l * 4) = o;
}

extern "C" void kernel_launch(void* const* d_in, const int* in_sizes, int n_in,
                              void* d_out, int out_size, void* d_ws, size_t ws_size,
                              hipStream_t stream) {
    const float* x       = (const float*)d_in[0];
    const float* h       = (const float*)d_in[1];
    const float* snorm_n = (const float*)d_in[2];
    const float* W1      = (const float*)d_in[4];
    const float* W2      = (const float*)d_in[5];
    const float* gamma   = (const float*)d_in[6];
    const float* beta    = (const float*)d_in[7];
    const int*   src     = (const int*)d_in[8];
    const int*   dst     = (const int*)d_in[9];
    float* out = (float*)d_out;

    const size_t NF = (size_t)NN * DD;       // 5.12M floats per node-array
    float* m_node = (float*)d_ws;            // [0 .. NF)
    float* P      = m_node + NF;             // [NF .. 2NF)
    float* Q      = m_node + 2 * NF;
    float* T      = m_node + 3 * NF;         // total 81.9 MB of ws

    hipMemsetAsync(m_node, 0, NF * sizeof(float), stream);
    pq_kernel<<<dim3(NTILES, 2), 256, 0, stream>>>(x, W1, P, Q);
    r_scatter<<<NE / BM, 256, 0, stream>>>(h, W1, P, Q, src, dst, m_node);
    t_kernel<<<NTILES, 256, 0, stream>>>(m_node, W2, T);
    final_kernel<<<NE / 8, 256, 0, stream>>>(T, snorm_n, gamma, beta, src, out);
}